// Round 14
// baseline (41678.714 us; speedup 1.0000x reference)
//
#include <hip/hip_runtime.h>

// ---------------------------------------------------------------------------
// Encoder: B=64, T=2048, D=256, U=256, UEP=64
//  ph1a: s1  = ln(x@W + b)     -> f16  [131072][768]
//  ph1b: s1e = ln(x@W_EP + b)  -> f64  [131072][192] (exact fp64)
//  R14 SPLIT (hep never depends on h):
//   Kernel A: EP scan. 64 WGs x 128 thr. EP weights in REGISTERS (128-thread
//     WG -> 512 VGPR/thread cap). fp64. Writes end_seq + fz[64][2048] table.
//   Kernel B: main GRU scan, fz precomputed -> no fp64/flag chain. 16 WGs x
//     4 batch rows: weight stream (384KB/step) amortized 4x. Uzr streamed
//     coalesced from L2 (no residency fight -> no spills), Uh LDS-resident.
// ---------------------------------------------------------------------------

typedef _Float16 h2  __attribute__((ext_vector_type(2)));
typedef _Float16 v8h __attribute__((ext_vector_type(8)));

__device__ __forceinline__ float fdot2_(h2 a, h2 b, float c) {
#if __has_builtin(__builtin_amdgcn_fdot2)
  return __builtin_amdgcn_fdot2(a, b, c, false);
#else
  return c + (float)a[0] * (float)b[0] + (float)a[1] * (float)b[1];
#endif
}

template <int I>
__device__ __forceinline__ h2 pr(v8h v) {
  h2 r; r[0] = v[2 * I]; r[1] = v[2 * I + 1]; return r;
}

// ---------------------------------------------------------------------------
// prep (R12-proven): wt j-major, uzr CHUNK-MAJOR [c][512][8], uh pages, wept.
// ---------------------------------------------------------------------------
__global__ __launch_bounds__(256) void prep_kernel(
    const float* __restrict__ W, const float* __restrict__ U,
    const float* __restrict__ W_EP,
    _Float16* __restrict__ wt, _Float16* __restrict__ uzr,
    _Float16* __restrict__ uh, float* __restrict__ wept)
{
  const int blk = blockIdx.x;
  const int k = threadIdx.x;
  if (blk < 768) {
    const int j = blk;
    wt[(size_t)j * 256 + k] = (_Float16)W[(size_t)k * 768 + j];
  } else if (blk < 1280) {
    const int j = blk - 768;
    const int c = k >> 3, e = k & 7;
    uzr[((size_t)c * 512 + j) * 8 + e] = (_Float16)U[(size_t)k * 768 + j];
  } else if (blk < 1536) {
    const int j = blk - 1280;
    const int p = k >> 3, e = k & 7;
    uh[((size_t)p * 256 + j) * 8 + e] = (_Float16)U[(size_t)k * 768 + 512 + j];
  } else {
    const int j = blk - 1536;
    wept[(size_t)j * 256 + k] = W_EP[(size_t)k * 192 + j];
  }
}

// ---------------------------------------------------------------------------
__global__ __launch_bounds__(256) void ph1_main_kernel(
    const float* __restrict__ x, const _Float16* __restrict__ wt,
    const float* __restrict__ bvec, const float* __restrict__ gam,
    const float* __restrict__ bet, _Float16* __restrict__ s1out)
{
  __shared__ __align__(16) _Float16 xs[16][256];
  __shared__ float sp[16][768];
  const int tid = threadIdx.x;
  const size_t row0 = (size_t)blockIdx.x * 16;

  #pragma unroll
  for (int i = 0; i < 16; ++i)
    xs[i][tid] = (_Float16)x[(row0 + i) * 256 + tid];
  __syncthreads();

  #pragma unroll 1
  for (int cc = 0; cc < 3; ++cc) {
    const int col = cc * 256 + tid;
    const v8h* wp = (const v8h*)(wt + (size_t)col * 256);
    float acc[16];
    #pragma unroll
    for (int r = 0; r < 16; ++r) acc[r] = 0.f;
    #pragma unroll 4
    for (int c = 0; c < 32; ++c) {
      const v8h w8 = wp[c];
      #pragma unroll
      for (int r = 0; r < 16; ++r) {
        const v8h x8 = *(const v8h*)(&xs[r][c * 8]);
        acc[r] = fdot2_(pr<0>(x8), pr<0>(w8), acc[r]);
        acc[r] = fdot2_(pr<1>(x8), pr<1>(w8), acc[r]);
        acc[r] = fdot2_(pr<2>(x8), pr<2>(w8), acc[r]);
        acc[r] = fdot2_(pr<3>(x8), pr<3>(w8), acc[r]);
      }
    }
    const float bb = bvec[col];
    #pragma unroll
    for (int r = 0; r < 16; ++r) sp[r][col] = acc[r] + bb;
  }
  __syncthreads();

  const int w = tid >> 6, lane = tid & 63;
  for (int rr = 0; rr < 4; ++rr) {
    const int r = (w << 2) | rr;
    float vals[12], sum = 0.f, sq = 0.f;
    #pragma unroll
    for (int j = 0; j < 12; ++j) {
      const float v = sp[r][lane + (j << 6)];
      vals[j] = v; sum += v; sq += v * v;
    }
    #pragma unroll
    for (int m = 32; m >= 1; m >>= 1) {
      sum += __shfl_xor(sum, m); sq += __shfl_xor(sq, m);
    }
    const float mean = sum * (1.f / 768.f);
    const float var = sq * (1.f / 768.f) - mean * mean;
    const float inv = 1.f / (sqrtf(var + 1e-5f) + 1e-5f);
    #pragma unroll
    for (int j = 0; j < 12; ++j) {
      const int c = lane + (j << 6);
      s1out[(row0 + r) * 768 + c] =
          (_Float16)(gam[c] * ((vals[j] - mean) * inv) + bet[c]);
    }
  }
}

// ---------------------------------------------------------------------------
__global__ __launch_bounds__(192) void ph1_ep_kernel(
    const float* __restrict__ x, const float* __restrict__ wept,
    const float* __restrict__ bvec, const float* __restrict__ gam,
    const float* __restrict__ bet, void* __restrict__ s1e, const int store64)
{
  __shared__ __align__(16) float xs[16][256];
  __shared__ double sp[16][192];
  const int tid = threadIdx.x;
  const size_t row0 = (size_t)blockIdx.x * 16;

  for (int idx = tid; idx < 4096; idx += 192)
    xs[idx >> 8][idx & 255] = x[row0 * 256 + idx];
  __syncthreads();

  {
    const float4* wp = (const float4*)(wept + (size_t)tid * 256);
    double acc[16];
    #pragma unroll
    for (int r = 0; r < 16; ++r) acc[r] = 0.0;
    #pragma unroll 2
    for (int c = 0; c < 64; ++c) {
      const float4 w4 = wp[c];
      #pragma unroll
      for (int r = 0; r < 16; ++r) {
        const float4 x4 = *(const float4*)(&xs[r][c * 4]);
        acc[r] += (double)x4.x * (double)w4.x;
        acc[r] += (double)x4.y * (double)w4.y;
        acc[r] += (double)x4.z * (double)w4.z;
        acc[r] += (double)x4.w * (double)w4.w;
      }
    }
    const double bb = (double)bvec[tid];
    #pragma unroll
    for (int r = 0; r < 16; ++r) sp[r][tid] = acc[r] + bb;
  }
  __syncthreads();

  const int w = tid >> 6, lane = tid & 63;
  for (int r = w; r < 16; r += 3) {
    double vals[3], sum = 0.0, sq = 0.0;
    #pragma unroll
    for (int j = 0; j < 3; ++j) {
      const double v = sp[r][lane + (j << 6)];
      vals[j] = v; sum += v; sq += v * v;
    }
    #pragma unroll
    for (int m = 32; m >= 1; m >>= 1) {
      sum += __shfl_xor(sum, m); sq += __shfl_xor(sq, m);
    }
    const double mean = sum * (1.0 / 192.0);
    const double var = sq * (1.0 / 192.0) - mean * mean;
    const double den = sqrt(var + 1e-5) + 1e-5;
    #pragma unroll
    for (int j = 0; j < 3; ++j) {
      const int c = lane + (j << 6);
      const double vv = (double)gam[c] * ((vals[j] - mean) / den) + (double)bet[c];
      if (store64) ((double*)s1e)[(row0 + r) * 192 + c] = vv;
      else         ((float*)s1e)[(row0 + r) * 192 + c] = (float)vv;
    }
  }
}

// ---------------------------------------------------------------------------
// Kernel A: EP scan. 64 WGs x 128 thr (2 waves). Weights fully in registers.
// ---------------------------------------------------------------------------
__global__ __launch_bounds__(128) void ep_scan_kernel(
    const float* __restrict__ U_EP, const void* __restrict__ s1e_v,
    const int s1e64, const int* __restrict__ mask,
    const float* __restrict__ gamep1, const float* __restrict__ betep1,
    const float* __restrict__ W1, const float* __restrict__ b1,
    float* __restrict__ out, float* __restrict__ fzw)
{
  __shared__ double hep[64];
  __shared__ double zeL[64];
  __shared__ double rhepL[64];
  __shared__ double prt[4];            // [w][0]=sum, [w][1]=sq

  const int t = threadIdx.x;           // 0..127
  const int b = blockIdx.x;
  const int lane = t & 63;
  const int w = t >> 6;

  float uez[64];
  #pragma unroll
  for (int k = 0; k < 64; ++k) uez[k] = U_EP[(size_t)k * 192 + t];
  float uehh[64];
  if (t < 64) {
    #pragma unroll
    for (int k = 0; k < 64; ++k) uehh[k] = U_EP[(size_t)k * 192 + 128 + t];
  }

  const float gse = gamep1[t],        bse = betep1[t];
  const float ghe = (t < 64) ? gamep1[128 + t] : 0.f;
  const float bhe = (t < 64) ? betep1[128 + t] : 0.f;
  const double w1d = (t >= 64) ? (double)W1[t - 64] : 0.0;
  const double b1d = (double)b1[0];
  const double* dptr = (const double*)s1e_v;
  const float*  fptr = (const float*)s1e_v;

  if (t < 64) hep[t] = 0.0;
  if (t == 0) fzw[(size_t)b * 2048] = 0.f;

  const size_t n0 = (size_t)b << 11;
  double s1ez_c = s1e64 ? dptr[n0 * 192 + t] : (double)fptr[n0 * 192 + t];
  double s1eh_c = 0.0;
  if (t < 64) s1eh_c = s1e64 ? dptr[n0 * 192 + 128 + t]
                             : (double)fptr[n0 * 192 + 128 + t];
  int mask_c = mask[n0];
  __syncthreads();

  for (int tt = 0; tt < 2048; ++tt) {
    const size_t n = ((size_t)b << 11) | (size_t)tt;
    const int ttn = (tt < 2047) ? tt + 1 : 2047;
    const size_t np1 = ((size_t)b << 11) | (size_t)ttn;
    const double s1ez_n = s1e64 ? dptr[np1 * 192 + t] : (double)fptr[np1 * 192 + t];
    double s1eh_n = 0.0;
    if (t < 64) s1eh_n = s1e64 ? dptr[np1 * 192 + 128 + t]
                               : (double)fptr[np1 * 192 + 128 + t];
    const int mask_n = mask[np1];

    // P1: zr dot (all 128 threads, col t) + is_end (wave 1)
    double d = 0.0;
    {
      const double2* hp = (const double2*)hep;
      #pragma unroll
      for (int k2 = 0; k2 < 32; ++k2) {
        const double2 h2v = hp[k2];
        d += h2v.x * (double)uez[2 * k2] + h2v.y * (double)uez[2 * k2 + 1];
      }
      double es = d, eq = d * d;
      #pragma unroll
      for (int m = 1; m <= 32; m <<= 1) { es += __shfl_xor(es, m); eq += __shfl_xor(eq, m); }
      if (lane == 0) { prt[w * 2] = es; prt[w * 2 + 1] = eq; }
    }
    if (w == 1) {
      double p = hep[lane] * w1d;
      #pragma unroll
      for (int m = 1; m <= 32; m <<= 1) p += __shfl_xor(p, m);
      if (t == 64) {
        const float e = ((p + b1d) > 0.0) ? 1.f : 0.f;
        if (tt < 2047) fzw[(size_t)b * 2048 + tt + 1] = e;
        out[(size_t)33554432 + n] = e;
      }
    }
    __syncthreads();  // B1

    // P2: LN128 -> se -> ze / rhep
    {
      const double S = prt[0] + prt[2];
      const double Q = prt[1] + prt[3];
      const double mean = S * (1.0 / 128.0);
      const double var = Q * (1.0 / 128.0) - mean * mean;
      const double den = sqrt(var + 1e-5) + 1e-5;
      const double s2e = (double)gse * ((d - mean) / den) + (double)bse;
      double se = 0.2 * (s1ez_c + s2e) + 0.5;
      se = fmin(fmax(se, 0.0), 1.0);
      if (t < 64) zeL[t] = se;
      else        rhepL[t - 64] = se * hep[t - 64];
    }
    __syncthreads();  // B2

    // P3: hh dot + LN64 + hep update (wave 0)
    if (t < 64) {
      const double2* rp = (const double2*)rhepL;
      double dh = 0.0;
      #pragma unroll
      for (int k2 = 0; k2 < 32; ++k2) {
        const double2 rv = rp[k2];
        dh += rv.x * (double)uehh[2 * k2] + rv.y * (double)uehh[2 * k2 + 1];
      }
      double es = dh, eq = dh * dh;
      #pragma unroll
      for (int m = 1; m <= 32; m <<= 1) { es += __shfl_xor(es, m); eq += __shfl_xor(eq, m); }
      const double mean = es * (1.0 / 64.0);
      const double var = eq * (1.0 / 64.0) - mean * mean;
      const double den = sqrt(var + 1e-5) + 1e-5;
      const double hhe = (double)ghe * ((dh - mean) / den) + (double)bhe;
      const double ze = zeL[t];
      const double hold = hep[t];
      const double hepn = ze * hold + (1.0 - ze) * tanh(s1eh_c + hhe);
      hep[t] = (mask_c > 0) ? hepn : hold;
    }
    __syncthreads();  // B3

    s1ez_c = s1ez_n; s1eh_c = s1eh_n; mask_c = mask_n;
  }
}

// ---------------------------------------------------------------------------
// Kernel B: main GRU scan. 16 WGs x 512 thr, 4 batch rows per WG.
// LDS map (dynamic, 143872 B)
// ---------------------------------------------------------------------------
#define OFFB_UH    0        /* 131072 f16 Uh pages [32][256][8]          */
#define OFFB_H2B   131072   /* 2048   f16 h [4 rows][256]                */
#define OFFB_RH2B  133120   /* 2048   f16 rh [4][256]                    */
#define OFFB_HF    135168   /* 4096   f32 h [4][256]                     */
#define OFFB_ZS    139264   /* 4096   f32 z [4][256]                     */
#define OFFB_ZRP   143360   /* 256    float2 zrP[8 waves][4 rows]        */
#define OFFB_HHP   143616   /* 128    float2 hhP[4][4]                   */
#define OFFB_LNZR  143744   /* 32     float2 lnzr[4]                     */
#define OFFB_LNHH  143776   /* 32     float2 lnhh[4]                     */
#define OFFB_FZ    143808   /* 32     f32 fzl[2][4]                      */
#define OFFB_MB    143840   /* 32     int mbl[2][4]                      */
#define SCANB_LDS_BYTES 143872

__global__ __launch_bounds__(512, 1) void main_scan_kernel(
    const _Float16* __restrict__ uzr_g, const _Float16* __restrict__ uh_g,
    const _Float16* __restrict__ s1, const int* __restrict__ mask,
    const float* __restrict__ fzw,
    const float* __restrict__ gam1, const float* __restrict__ bet1,
    float* __restrict__ out)
{
  extern __shared__ char sm[];
  const int t = threadIdx.x;
  const int w = t >> 6;
  const int b0 = blockIdx.x * 4;

  float* hf   = (float*)(sm + OFFB_HF);
  float* zs   = (float*)(sm + OFFB_ZS);
  float* fzl  = (float*)(sm + OFFB_FZ);
  int*   mbl  = (int*)(sm + OFFB_MB);

  // stage Uh
  {
    const v8h* src = (const v8h*)uh_g;
    v8h* dst = (v8h*)(sm + OFFB_UH);
    #pragma unroll
    for (int i = 0; i < 16; ++i) dst[i * 512 + t] = src[i * 512 + t];
  }

  const float gz = gam1[t], bz = bet1[t];
  const float gh = (t < 256) ? gam1[512 + t] : 0.f;
  const float bh = (t < 256) ? bet1[512 + t] : 0.f;

  // init state
  if (t < 256) {
    #pragma unroll
    for (int r = 0; r < 4; ++r) {
      hf[r * 256 + t] = 0.f;
      ((_Float16*)(sm + OFFB_H2B))[r * 256 + t] = (_Float16)0.f;
    }
  }
  if (t < 4)      fzl[t] = fzw[(size_t)(b0 + t) * 2048];
  else if (t < 8) mbl[t - 4] = mask[(size_t)(b0 + t - 4) << 11];

  // prefetch s1 (step 0)
  float s1z_c[4], s1h_c[4];
  #pragma unroll
  for (int r = 0; r < 4; ++r) {
    const size_t nr = (size_t)(b0 + r) << 11;
    s1z_c[r] = (float)s1[nr * 768 + t];
    s1h_c[r] = (t < 256) ? (float)s1[nr * 768 + 512 + t] : 0.f;
  }
  __syncthreads();

  for (int tt = 0; tt < 2048; ++tt) {
    float fzr[4]; int xm[4];
    #pragma unroll
    for (int r = 0; r < 4; ++r) {
      fzr[r] = (fzl[(tt & 1) * 4 + r] > 0.5f) ? 0.f : 1.f;
      xm[r]  = mbl[(tt & 1) * 4 + r];
    }

    // ---- P1: deferred h-out | prefetch | zr dots ----
    if (tt > 0 && t >= 256) {
      const int u = t - 256;
      #pragma unroll
      for (int r = 0; r < 4; ++r) {
        const size_t nr = ((size_t)(b0 + r) << 11) | (size_t)(tt - 1);
        out[nr * 256 + u] = hf[r * 256 + u];
      }
    }
    const int ttn = (tt < 2047) ? tt + 1 : 2047;
    float s1z_n[4], s1h_n[4];
    #pragma unroll
    for (int r = 0; r < 4; ++r) {
      const size_t nr = ((size_t)(b0 + r) << 11) | (size_t)ttn;
      s1z_n[r] = (float)s1[nr * 768 + t];
      s1h_n[r] = (t < 256) ? (float)s1[nr * 768 + 512 + t] : 0.f;
    }
    float fz_pf = 0.f; int mb_pf = 0;
    if (t < 4)      fz_pf = fzw[(size_t)(b0 + t) * 2048 + ttn];
    else if (t < 8) mb_pf = mask[((size_t)(b0 + t - 4) << 11) + ttn];

    float acc[4];
    #pragma unroll
    for (int r = 0; r < 4; ++r) acc[r] = 0.f;
    {
      const v8h* uzb = (const v8h*)uzr_g;
      const v8h* hb  = (const v8h*)(sm + OFFB_H2B);
      #pragma unroll 4
      for (int c = 0; c < 32; ++c) {
        const v8h wc = uzb[(size_t)c * 512 + t];
        #pragma unroll
        for (int r = 0; r < 4; ++r) {
          const v8h hc = hb[r * 32 + c];
          acc[r] = fdot2_(pr<0>(hc), pr<0>(wc), acc[r]);
          acc[r] = fdot2_(pr<1>(hc), pr<1>(wc), acc[r]);
          acc[r] = fdot2_(pr<2>(hc), pr<2>(wc), acc[r]);
          acc[r] = fdot2_(pr<3>(hc), pr<3>(wc), acc[r]);
        }
      }
    }
    #pragma unroll
    for (int r = 0; r < 4; ++r) {
      acc[r] *= fzr[r];
      float s_ = acc[r], q_ = acc[r] * acc[r];
      #pragma unroll
      for (int m = 1; m <= 32; m <<= 1) { s_ += __shfl_xor(s_, m); q_ += __shfl_xor(q_, m); }
      if ((t & 63) == 0) ((float2*)(sm + OFFB_ZRP))[w * 4 + r] = make_float2(s_, q_);
    }
    __syncthreads();  // B1

    // ---- P2: LN512 finalize (4 threads) ----
    if (t < 4) {
      const float2* zp = (const float2*)(sm + OFFB_ZRP);
      float S = 0.f, Q = 0.f;
      #pragma unroll
      for (int i = 0; i < 8; ++i) { S += zp[i * 4 + t].x; Q += zp[i * 4 + t].y; }
      const float mean = S * (1.f / 512.f);
      const float var = Q * (1.f / 512.f) - mean * mean;
      const float inv = 1.f / (sqrtf(var + 1e-5f) + 1e-5f);
      ((float2*)(sm + OFFB_LNZR))[t] = make_float2(mean, inv);
    }
    __syncthreads();  // B2

    // ---- P3: z / rh ----
    #pragma unroll
    for (int r = 0; r < 4; ++r) {
      const float2 ln = ((const float2*)(sm + OFFB_LNZR))[r];
      const float s2v = gz * ((acc[r] - ln.x) * ln.y) + bz;
      float sv = 0.2f * (s1z_c[r] + s2v) + 0.5f;
      sv = fminf(fmaxf(sv, 0.f), 1.f);
      if (t < 256) zs[r * 256 + t] = sv;
      else {
        const float rhv = sv * (fzr[r] * hf[r * 256 + (t - 256)]);
        ((_Float16*)(sm + OFFB_RH2B))[r * 256 + (t - 256)] = (_Float16)rhv;
      }
    }
    __syncthreads();  // B3

    // ---- P4: hh dots (threads 0..255) ----
    float hacc[4];
    #pragma unroll
    for (int r = 0; r < 4; ++r) hacc[r] = 0.f;
    if (t < 256) {
      const v8h* uhv = (const v8h*)(sm + OFFB_UH);
      const v8h* rb  = (const v8h*)(sm + OFFB_RH2B);
      #pragma unroll 4
      for (int c = 0; c < 32; ++c) {
        const v8h uc = uhv[c * 256 + t];
        #pragma unroll
        for (int r = 0; r < 4; ++r) {
          const v8h rc = rb[r * 32 + c];
          hacc[r] = fdot2_(pr<0>(rc), pr<0>(uc), hacc[r]);
          hacc[r] = fdot2_(pr<1>(rc), pr<1>(uc), hacc[r]);
          hacc[r] = fdot2_(pr<2>(rc), pr<2>(uc), hacc[r]);
          hacc[r] = fdot2_(pr<3>(rc), pr<3>(uc), hacc[r]);
        }
      }
      #pragma unroll
      for (int r = 0; r < 4; ++r) {
        float s_ = hacc[r], q_ = hacc[r] * hacc[r];
        #pragma unroll
        for (int m = 1; m <= 32; m <<= 1) { s_ += __shfl_xor(s_, m); q_ += __shfl_xor(q_, m); }
        if ((t & 63) == 0) ((float2*)(sm + OFFB_HHP))[w * 4 + r] = make_float2(s_, q_);
      }
    }
    __syncthreads();  // B4

    // ---- P5: LN256 finalize (4 threads) ----
    if (t < 4) {
      const float2* hp = (const float2*)(sm + OFFB_HHP);
      float S = 0.f, Q = 0.f;
      #pragma unroll
      for (int i = 0; i < 4; ++i) { S += hp[i * 4 + t].x; Q += hp[i * 4 + t].y; }
      const float mean = S * (1.f / 256.f);
      const float var = Q * (1.f / 256.f) - mean * mean;
      const float inv = 1.f / (sqrtf(var + 1e-5f) + 1e-5f);
      ((float2*)(sm + OFFB_LNHH))[t] = make_float2(mean, inv);
    }
    __syncthreads();  // B5

    // ---- P6: h update | publish next-step fz/mask ----
    if (t < 256) {
      #pragma unroll
      for (int r = 0; r < 4; ++r) {
        const float2 ln = ((const float2*)(sm + OFFB_LNHH))[r];
        const float hhv = gh * ((hacc[r] - ln.x) * ln.y) + bh;
        const float z = zs[r * 256 + t];
        const float hz = fzr[r] * hf[r * 256 + t];
        const float hn = z * hz + (1.f - z) * tanhf(s1h_c[r] + hhv);
        const float hc = (xm[r] > 0) ? hn : hz;
        hf[r * 256 + t] = hc;
        ((_Float16*)(sm + OFFB_H2B))[r * 256 + t] = (_Float16)hc;
      }
    } else if (t < 260) {
      fzl[((tt + 1) & 1) * 4 + (t - 256)] = 0.f;  // placeholder overwritten below
    }
    if (t < 4)      fzl[((tt + 1) & 1) * 4 + t] = fz_pf;
    else if (t < 8) mbl[((tt + 1) & 1) * 4 + (t - 4)] = mb_pf;
    __syncthreads();  // B6

    #pragma unroll
    for (int r = 0; r < 4; ++r) { s1z_c[r] = s1z_n[r]; s1h_c[r] = s1h_n[r]; }
  }
  // final h write (step 2047)
  if (t >= 256) {
    const int u = t - 256;
    #pragma unroll
    for (int r = 0; r < 4; ++r) {
      const size_t nr = ((size_t)(b0 + r) << 11) | (size_t)2047;
      out[nr * 256 + u] = hf[r * 256 + u];
    }
  }
}

// ---------------------------------------------------------------------------
extern "C" void kernel_launch(void* const* d_in, const int* in_sizes, int n_in,
                              void* d_out, int out_size, void* d_ws, size_t ws_size,
                              hipStream_t stream)
{
  (void)in_sizes; (void)n_in; (void)out_size;
  const float* x       = (const float*)d_in[0];
  const int*   mask    = (const int*)d_in[1];
  const float* W       = (const float*)d_in[2];
  const float* U       = (const float*)d_in[3];
  const float* bvec    = (const float*)d_in[4];
  const float* gammas  = (const float*)d_in[5];
  const float* betas   = (const float*)d_in[6];
  const float* W_EP    = (const float*)d_in[7];
  const float* U_EP    = (const float*)d_in[8];
  const float* b_EP    = (const float*)d_in[9];
  const float* gammasE = (const float*)d_in[10];
  const float* betasE  = (const float*)d_in[11];
  const float* W1_EP   = (const float*)d_in[12];
  const float* b1_EP   = (const float*)d_in[13];
  float* out = (float*)d_out;

  const size_t NR = 131072;                 // B*T
  const size_t S1_SZ    = NR * 768 * 2;     // f16
  const size_t S1E64_SZ = NR * 192 * 8;     // f64
  const size_t S1E32_SZ = NR * 192 * 4;     // f32 fallback
  const size_t WSMALL = 262144 + 131072 + 393216 + 196608 + 524288;
  const int s1e64 = (ws_size >= S1_SZ + S1E64_SZ + WSMALL) ? 1 : 0;
  const size_t S1E_SZ = s1e64 ? S1E64_SZ : S1E32_SZ;
  if (ws_size < S1_SZ + S1E32_SZ + WSMALL) return;  // cannot run

  char* ws = (char*)d_ws;
  size_t off = 0;
  void* s1e      = (void*)(ws + off);      off += S1E_SZ;
  _Float16* s1   = (_Float16*)(ws + off);  off += S1_SZ;
  _Float16* uzr  = (_Float16*)(ws + off);  off += 262144;
  _Float16* uh   = (_Float16*)(ws + off);  off += 131072;
  _Float16* wt   = (_Float16*)(ws + off);  off += 393216;
  float* wept    = (float*)(ws + off);     off += 196608;
  float* fzw     = (float*)(ws + off);     off += 524288;

  prep_kernel<<<dim3(1728), dim3(256), 0, stream>>>(
      W, U, W_EP, wt, uzr, uh, wept);
  ph1_main_kernel<<<dim3(8192), dim3(256), 0, stream>>>(
      x, wt, bvec, gammas, betas, s1);
  ph1_ep_kernel<<<dim3(8192), dim3(192), 0, stream>>>(
      x, wept, b_EP, gammasE, betasE, s1e, s1e64);

  ep_scan_kernel<<<dim3(64), dim3(128), 0, stream>>>(
      U_EP, (const void*)s1e, s1e64, mask,
      gammasE + 192, betasE + 192, W1_EP, b1_EP, out, fzw);

  hipFuncSetAttribute(reinterpret_cast<const void*>(main_scan_kernel),
                      hipFuncAttributeMaxDynamicSharedMemorySize, SCANB_LDS_BYTES);
  main_scan_kernel<<<dim3(16), dim3(512), SCANB_LDS_BYTES, stream>>>(
      uzr, uh, s1, mask, fzw, gammas + 768, betas + 768, out);
}

// Round 15
// 16699.782 us; speedup vs baseline: 2.4958x; 2.4958x over previous
//
#include <hip/hip_runtime.h>

// ---------------------------------------------------------------------------
// Encoder: B=64, T=2048, D=256, U=256, UEP=64
//  ph1a: s1  = ln(x@W + b)    -> f16 [131072][768]
//  ph1b: s1e = ln(x@W_EP + b) -> f64 [131072][192] (exact fp64)
//  R15:
//   ep_scan:   64 WGs x 64 thr (1 wave). ZERO barriers/LDS in loop: hep in
//              lane regs, readlane broadcasts, shfl reductions, weights in
//              192 f32 regs. fp64 (is_end must match round(sigmoid)).
//              Writes end_seq + fz table.
//   main_scan: 64 WGs x 512 thr, 1 row/WG (R6 shape), clean (no EP -> ~90
//              VGPR, no spills), Uzr streamed from L2 with DEPTH-8 pipelined
//              ring (R14 failed only because its stream was unpipelined).
//              Uh LDS-resident. Math bit-identical to R6's proven path.
// ---------------------------------------------------------------------------

typedef _Float16 h2  __attribute__((ext_vector_type(2)));
typedef _Float16 v8h __attribute__((ext_vector_type(8)));

__device__ __forceinline__ float fdot2_(h2 a, h2 b, float c) {
#if __has_builtin(__builtin_amdgcn_fdot2)
  return __builtin_amdgcn_fdot2(a, b, c, false);
#else
  return c + (float)a[0] * (float)b[0] + (float)a[1] * (float)b[1];
#endif
}

template <int I>
__device__ __forceinline__ h2 pr(v8h v) {
  h2 r; r[0] = v[2 * I]; r[1] = v[2 * I + 1]; return r;
}

__device__ __forceinline__ double bcast_d(double v, int k) {
  const int2 p = __builtin_bit_cast(int2, v);
  int2 q;
  q.x = __builtin_amdgcn_readlane(p.x, k);
  q.y = __builtin_amdgcn_readlane(p.y, k);
  return __builtin_bit_cast(double, q);
}

// Raw barrier: order LDS (lgkmcnt) but leave global loads/stores in flight.
__device__ __forceinline__ void wg_barrier() {
  __builtin_amdgcn_sched_barrier(0);
  asm volatile("s_waitcnt lgkmcnt(0)" ::: "memory");
  __builtin_amdgcn_sched_barrier(0);
  __builtin_amdgcn_s_barrier();
  __builtin_amdgcn_sched_barrier(0);
}

// ---------------------------------------------------------------------------
// prep: wt j-major, uzr CHUNK-MAJOR [c][512][8], uh pages [p][256][8], wept.
// ---------------------------------------------------------------------------
__global__ __launch_bounds__(256) void prep_kernel(
    const float* __restrict__ W, const float* __restrict__ U,
    const float* __restrict__ W_EP,
    _Float16* __restrict__ wt, _Float16* __restrict__ uzr,
    _Float16* __restrict__ uh, float* __restrict__ wept)
{
  const int blk = blockIdx.x;
  const int k = threadIdx.x;
  if (blk < 768) {
    const int j = blk;
    wt[(size_t)j * 256 + k] = (_Float16)W[(size_t)k * 768 + j];
  } else if (blk < 1280) {
    const int j = blk - 768;
    const int c = k >> 3, e = k & 7;
    uzr[((size_t)c * 512 + j) * 8 + e] = (_Float16)U[(size_t)k * 768 + j];
  } else if (blk < 1536) {
    const int j = blk - 1280;
    const int p = k >> 3, e = k & 7;
    uh[((size_t)p * 256 + j) * 8 + e] = (_Float16)U[(size_t)k * 768 + 512 + j];
  } else {
    const int j = blk - 1536;
    wept[(size_t)j * 256 + k] = W_EP[(size_t)k * 192 + j];
  }
}

// ---------------------------------------------------------------------------
__global__ __launch_bounds__(256) void ph1_main_kernel(
    const float* __restrict__ x, const _Float16* __restrict__ wt,
    const float* __restrict__ bvec, const float* __restrict__ gam,
    const float* __restrict__ bet, _Float16* __restrict__ s1out)
{
  __shared__ __align__(16) _Float16 xs[16][256];
  __shared__ float sp[16][768];
  const int tid = threadIdx.x;
  const size_t row0 = (size_t)blockIdx.x * 16;

  #pragma unroll
  for (int i = 0; i < 16; ++i)
    xs[i][tid] = (_Float16)x[(row0 + i) * 256 + tid];
  __syncthreads();

  #pragma unroll 1
  for (int cc = 0; cc < 3; ++cc) {
    const int col = cc * 256 + tid;
    const v8h* wp = (const v8h*)(wt + (size_t)col * 256);
    float acc[16];
    #pragma unroll
    for (int r = 0; r < 16; ++r) acc[r] = 0.f;
    #pragma unroll 4
    for (int c = 0; c < 32; ++c) {
      const v8h w8 = wp[c];
      #pragma unroll
      for (int r = 0; r < 16; ++r) {
        const v8h x8 = *(const v8h*)(&xs[r][c * 8]);
        acc[r] = fdot2_(pr<0>(x8), pr<0>(w8), acc[r]);
        acc[r] = fdot2_(pr<1>(x8), pr<1>(w8), acc[r]);
        acc[r] = fdot2_(pr<2>(x8), pr<2>(w8), acc[r]);
        acc[r] = fdot2_(pr<3>(x8), pr<3>(w8), acc[r]);
      }
    }
    const float bb = bvec[col];
    #pragma unroll
    for (int r = 0; r < 16; ++r) sp[r][col] = acc[r] + bb;
  }
  __syncthreads();

  const int w = tid >> 6, lane = tid & 63;
  for (int rr = 0; rr < 4; ++rr) {
    const int r = (w << 2) | rr;
    float vals[12], sum = 0.f, sq = 0.f;
    #pragma unroll
    for (int j = 0; j < 12; ++j) {
      const float v = sp[r][lane + (j << 6)];
      vals[j] = v; sum += v; sq += v * v;
    }
    #pragma unroll
    for (int m = 32; m >= 1; m >>= 1) {
      sum += __shfl_xor(sum, m); sq += __shfl_xor(sq, m);
    }
    const float mean = sum * (1.f / 768.f);
    const float var = sq * (1.f / 768.f) - mean * mean;
    const float inv = 1.f / (sqrtf(var + 1e-5f) + 1e-5f);
    #pragma unroll
    for (int j = 0; j < 12; ++j) {
      const int c = lane + (j << 6);
      s1out[(row0 + r) * 768 + c] =
          (_Float16)(gam[c] * ((vals[j] - mean) * inv) + bet[c]);
    }
  }
}

// ---------------------------------------------------------------------------
__global__ __launch_bounds__(192) void ph1_ep_kernel(
    const float* __restrict__ x, const float* __restrict__ wept,
    const float* __restrict__ bvec, const float* __restrict__ gam,
    const float* __restrict__ bet, void* __restrict__ s1e, const int store64)
{
  __shared__ __align__(16) float xs[16][256];
  __shared__ double sp[16][192];
  const int tid = threadIdx.x;
  const size_t row0 = (size_t)blockIdx.x * 16;

  for (int idx = tid; idx < 4096; idx += 192)
    xs[idx >> 8][idx & 255] = x[row0 * 256 + idx];
  __syncthreads();

  {
    const float4* wp = (const float4*)(wept + (size_t)tid * 256);
    double acc[16];
    #pragma unroll
    for (int r = 0; r < 16; ++r) acc[r] = 0.0;
    #pragma unroll 2
    for (int c = 0; c < 64; ++c) {
      const float4 w4 = wp[c];
      #pragma unroll
      for (int r = 0; r < 16; ++r) {
        const float4 x4 = *(const float4*)(&xs[r][c * 4]);
        acc[r] += (double)x4.x * (double)w4.x;
        acc[r] += (double)x4.y * (double)w4.y;
        acc[r] += (double)x4.z * (double)w4.z;
        acc[r] += (double)x4.w * (double)w4.w;
      }
    }
    const double bb = (double)bvec[tid];
    #pragma unroll
    for (int r = 0; r < 16; ++r) sp[r][tid] = acc[r] + bb;
  }
  __syncthreads();

  const int w = tid >> 6, lane = tid & 63;
  for (int r = w; r < 16; r += 3) {
    double vals[3], sum = 0.0, sq = 0.0;
    #pragma unroll
    for (int j = 0; j < 3; ++j) {
      const double v = sp[r][lane + (j << 6)];
      vals[j] = v; sum += v; sq += v * v;
    }
    #pragma unroll
    for (int m = 32; m >= 1; m >>= 1) {
      sum += __shfl_xor(sum, m); sq += __shfl_xor(sq, m);
    }
    const double mean = sum * (1.0 / 192.0);
    const double var = sq * (1.0 / 192.0) - mean * mean;
    const double den = sqrt(var + 1e-5) + 1e-5;
    #pragma unroll
    for (int j = 0; j < 3; ++j) {
      const int c = lane + (j << 6);
      const double vv = (double)gam[c] * ((vals[j] - mean) / den) + (double)bet[c];
      if (store64) ((double*)s1e)[(row0 + r) * 192 + c] = vv;
      else         ((float*)s1e)[(row0 + r) * 192 + c] = (float)vv;
    }
  }
}

// ---------------------------------------------------------------------------
// ep_scan: 64 WGs x 64 thr (1 wave). No barriers, no LDS in loop.
// lane l owns zr cols l and 64+l, hh col 128+l; hep[l] in lane l's register.
// ---------------------------------------------------------------------------
__global__ __launch_bounds__(64) void ep_scan_kernel(
    const float* __restrict__ U_EP, const void* __restrict__ s1e_v,
    const int s1e64, const int* __restrict__ mask,
    const float* __restrict__ gamep1, const float* __restrict__ betep1,
    const float* __restrict__ W1, const float* __restrict__ b1,
    float* __restrict__ out, float* __restrict__ fzw)
{
  const int l = threadIdx.x;           // 0..63
  const int b = blockIdx.x;

  float uezA[64], uezB[64], uehh[64];
  #pragma unroll
  for (int k = 0; k < 64; ++k) uezA[k] = U_EP[(size_t)k * 192 + l];
  #pragma unroll
  for (int k = 0; k < 64; ++k) uezB[k] = U_EP[(size_t)k * 192 + 64 + l];
  #pragma unroll
  for (int k = 0; k < 64; ++k) uehh[k] = U_EP[(size_t)k * 192 + 128 + l];

  const double gseA = (double)gamep1[l],       bseA = (double)betep1[l];
  const double gseB = (double)gamep1[64 + l],  bseB = (double)betep1[64 + l];
  const double ghe  = (double)gamep1[128 + l], bhe  = (double)betep1[128 + l];
  const double w1d = (double)W1[l];
  const double b1d = (double)b1[0];
  const double* dptr = (const double*)s1e_v;
  const float*  fptr = (const float*)s1e_v;

  double hep = 0.0;
  if (l == 0) fzw[(size_t)b * 2048] = 0.f;

  const size_t n0 = (size_t)b << 11;
  double s1eA_c = s1e64 ? dptr[n0 * 192 + l]       : (double)fptr[n0 * 192 + l];
  double s1eB_c = s1e64 ? dptr[n0 * 192 + 64 + l]  : (double)fptr[n0 * 192 + 64 + l];
  double s1eh_c = s1e64 ? dptr[n0 * 192 + 128 + l] : (double)fptr[n0 * 192 + 128 + l];
  int mask_c = mask[n0];

  for (int tt = 0; tt < 2048; ++tt) {
    const size_t n = ((size_t)b << 11) | (size_t)tt;
    const int ttn = (tt < 2047) ? tt + 1 : 2047;
    const size_t np1 = ((size_t)b << 11) | (size_t)ttn;
    const double s1eA_n = s1e64 ? dptr[np1 * 192 + l]       : (double)fptr[np1 * 192 + l];
    const double s1eB_n = s1e64 ? dptr[np1 * 192 + 64 + l]  : (double)fptr[np1 * 192 + 64 + l];
    const double s1eh_n = s1e64 ? dptr[np1 * 192 + 128 + l] : (double)fptr[np1 * 192 + 128 + l];
    const int mask_n = mask[np1];

    // is_end from hep entering this step
    {
      double p = hep * w1d;
      #pragma unroll
      for (int m = 1; m <= 32; m <<= 1) p += __shfl_xor(p, m);
      if (l == 0) {
        const float e = ((p + b1d) > 0.0) ? 1.f : 0.f;
        if (tt < 2047) fzw[(size_t)b * 2048 + tt + 1] = e;
        out[(size_t)33554432 + n] = e;
      }
    }

    // zr dots via lane broadcast of hep
    double dA = 0.0, dB = 0.0;
    #pragma unroll
    for (int k = 0; k < 64; ++k) {
      const double hk = bcast_d(hep, k);
      dA += hk * (double)uezA[k];
      dB += hk * (double)uezB[k];
    }
    // LN over 128 (2 cols per lane)
    {
      double S = dA + dB, Q = dA * dA + dB * dB;
      #pragma unroll
      for (int m = 1; m <= 32; m <<= 1) { S += __shfl_xor(S, m); Q += __shfl_xor(Q, m); }
      const double mean = S * (1.0 / 128.0);
      const double var = Q * (1.0 / 128.0) - mean * mean;
      const double den = sqrt(var + 1e-5) + 1e-5;
      double seA = 0.2 * (s1eA_c + (gseA * ((dA - mean) / den) + bseA)) + 0.5;
      seA = fmin(fmax(seA, 0.0), 1.0);                  // z_e[l]
      double seB = 0.2 * (s1eB_c + (gseB * ((dB - mean) / den) + bseB)) + 0.5;
      seB = fmin(fmax(seB, 0.0), 1.0);                  // r_e[l]
      const double rh = seB * hep;                      // (r*h)[l]

      // hh dot via lane broadcast of rh
      double dh = 0.0;
      #pragma unroll
      for (int k = 0; k < 64; ++k) {
        const double rk = bcast_d(rh, k);
        dh += rk * (double)uehh[k];
      }
      double S2 = dh, Q2 = dh * dh;
      #pragma unroll
      for (int m = 1; m <= 32; m <<= 1) { S2 += __shfl_xor(S2, m); Q2 += __shfl_xor(Q2, m); }
      const double mean2 = S2 * (1.0 / 64.0);
      const double var2 = Q2 * (1.0 / 64.0) - mean2 * mean2;
      const double den2 = sqrt(var2 + 1e-5) + 1e-5;
      const double hhe = ghe * ((dh - mean2) / den2) + bhe;
      const double hepn = seA * hep + (1.0 - seA) * tanh(s1eh_c + hhe);
      hep = (mask_c > 0) ? hepn : hep;
    }

    s1eA_c = s1eA_n; s1eB_c = s1eB_n; s1eh_c = s1eh_n; mask_c = mask_n;
  }
}

// ---------------------------------------------------------------------------
// main_scan: 64 WGs x 512 thr, 1 row/WG. Uzr depth-8 pipelined L2 stream.
// LDS map (dynamic, 133248 B)
// ---------------------------------------------------------------------------
#define OFFM_UH   0        /* 131072 f16 Uh pages [32][256][8]   */
#define OFFM_H2   131072   /* 512    f16 h packed h2[128]        */
#define OFFM_RH   131584   /* 512    f16 rh packed               */
#define OFFM_HF   132096   /* 1024   f32 h[256]                  */
#define OFFM_ZRP  133120   /* 64     float2 zrP[8]               */
#define OFFM_HHP  133184   /* 32     float2 hhP[4]               */
#define SCANM_LDS_BYTES 133248

__global__ __launch_bounds__(512, 2) void main_scan_kernel(
    const _Float16* __restrict__ uzr_g, const _Float16* __restrict__ uh_g,
    const _Float16* __restrict__ s1, const int* __restrict__ mask,
    const float* __restrict__ fzw,
    const float* __restrict__ gam1, const float* __restrict__ bet1,
    float* __restrict__ out)
{
  extern __shared__ char sm[];
  const int t = threadIdx.x;
  const int b = blockIdx.x;
  const int w = t >> 6;

  float* hf = (float*)(sm + OFFM_HF);

  // stage Uh
  {
    const v8h* src = (const v8h*)uh_g;
    v8h* dst = (v8h*)(sm + OFFM_UH);
    #pragma unroll
    for (int i = 0; i < 16; ++i) dst[i * 512 + t] = src[i * 512 + t];
  }

  const float gz = gam1[t], bz = bet1[t];
  const float gh = (t < 256) ? gam1[512 + t] : 0.f;
  const float bh = (t < 256) ? bet1[512 + t] : 0.f;

  if (t < 128) { h2 z2; z2[0] = (_Float16)0.f; z2[1] = (_Float16)0.f;
                 ((h2*)(sm + OFFM_H2))[t] = z2; }
  if (t < 256) hf[t] = 0.f;

  const size_t n0 = (size_t)b << 11;
  float s1z_c = (float)s1[n0 * 768 + t];
  float s1h_c = (t < 256) ? (float)s1[n0 * 768 + 512 + t] : 0.f;
  float fz_c = fzw[(size_t)b * 2048];
  int   xm_c = mask[n0];
  __syncthreads();

  for (int tt = 0; tt < 2048; ++tt) {
    const size_t n = ((size_t)b << 11) | (size_t)tt;
    const float fz = (fz_c > 0.5f) ? 0.f : 1.f;
    const int xm = xm_c;

    // ---- P1: deferred out | prefetch t+1 | pipelined zr dot ----
    if (tt > 0 && t < 256) out[(n - 1) * 256 + t] = hf[t];

    const int ttn = (tt < 2047) ? tt + 1 : 2047;
    const size_t np1 = ((size_t)b << 11) | (size_t)ttn;
    const float s1z_n = (float)s1[np1 * 768 + t];
    const float s1h_n = (t < 256) ? (float)s1[np1 * 768 + 512 + t] : 0.f;
    const float fz_n = fzw[(size_t)b * 2048 + ttn];
    const int   xm_n = mask[np1];

    // depth-8 pipelined stream of column t of Uzr (chunk-major)
    const v8h* uzb = (const v8h*)uzr_g;
    asm volatile("" : "+v"(uzb));      // defeat LICM hoist-then-spill
    v8h wz[8];
    #pragma unroll
    for (int q = 0; q < 8; ++q) wz[q] = uzb[(size_t)q * 512 + t];

    const v8h* hv = (const v8h*)(sm + OFFM_H2);
    float a0 = 0.f, a1 = 0.f, a2 = 0.f, a3 = 0.f;
    #pragma unroll
    for (int k = 0; k < 32; ++k) {
      const v8h hc = hv[k];
      const v8h wc = wz[k & 7];
      a0 = fdot2_(pr<0>(hc), pr<0>(wc), a0);
      a1 = fdot2_(pr<1>(hc), pr<1>(wc), a1);
      a2 = fdot2_(pr<2>(hc), pr<2>(wc), a2);
      a3 = fdot2_(pr<3>(hc), pr<3>(wc), a3);
      if (k < 24) wz[k & 7] = uzb[(size_t)(k + 8) * 512 + t];
    }
    const float d = ((a0 + a1) + (a2 + a3)) * fz;
    {
      float s_ = d, q_ = d * d;
      #pragma unroll
      for (int m = 1; m <= 32; m <<= 1) { s_ += __shfl_xor(s_, m); q_ += __shfl_xor(q_, m); }
      if ((t & 63) == 0) ((float2*)(sm + OFFM_ZRP))[w] = make_float2(s_, q_);
    }
    wg_barrier();  // B1

    // ---- P2: LN512 -> z(reg)/rh ----
    float zreg = 0.f;
    {
      float S = 0.f, Q = 0.f;
      const float4* zp = (const float4*)(sm + OFFM_ZRP);
      #pragma unroll
      for (int i = 0; i < 4; ++i) { const float4 v = zp[i]; S += v.x + v.z; Q += v.y + v.w; }
      const float mean = S * (1.f / 512.f);
      const float var = Q * (1.f / 512.f) - mean * mean;
      const float inv = 1.f / (sqrtf(var + 1e-5f) + 1e-5f);
      const float s2v = gz * ((d - mean) * inv) + bz;
      float sv = 0.2f * (s1z_c + s2v) + 0.5f;
      sv = fminf(fmaxf(sv, 0.f), 1.f);
      if (t < 256) zreg = sv;
      else {
        const float rhv = sv * (fz * hf[t - 256]);
        ((_Float16*)(sm + OFFM_RH))[t - 256] = (_Float16)rhv;
      }
    }
    wg_barrier();  // B2

    // ---- P3: hh dot (t<256) ----
    float dh = 0.f;
    if (t < 256) {
      const v8h* rhv8 = (const v8h*)(sm + OFFM_RH);
      const v8h* uhv  = (const v8h*)(sm + OFFM_UH);
      float c0 = 0.f, c1 = 0.f, c2 = 0.f, c3 = 0.f;
      #pragma unroll
      for (int p = 0; p < 32; ++p) {
        const v8h rc = rhv8[p];
        const v8h uc = uhv[p * 256 + t];
        c0 = fdot2_(pr<0>(rc), pr<0>(uc), c0);
        c1 = fdot2_(pr<1>(rc), pr<1>(uc), c1);
        c2 = fdot2_(pr<2>(rc), pr<2>(uc), c2);
        c3 = fdot2_(pr<3>(rc), pr<3>(uc), c3);
      }
      dh = (c0 + c1) + (c2 + c3);
      float s_ = dh, q_ = dh * dh;
      #pragma unroll
      for (int m = 1; m <= 32; m <<= 1) { s_ += __shfl_xor(s_, m); q_ += __shfl_xor(q_, m); }
      if ((t & 63) == 0) ((float2*)(sm + OFFM_HHP))[w] = make_float2(s_, q_);
    }
    wg_barrier();  // B3

    // ---- P4: h update (t<256) ----
    if (t < 256) {
      float S = 0.f, Q = 0.f;
      const float4* hp4 = (const float4*)(sm + OFFM_HHP);
      #pragma unroll
      for (int i = 0; i < 2; ++i) { const float4 v = hp4[i]; S += v.x + v.z; Q += v.y + v.w; }
      const float mean = S * (1.f / 256.f);
      const float var = Q * (1.f / 256.f) - mean * mean;
      const float inv = 1.f / (sqrtf(var + 1e-5f) + 1e-5f);
      const float hhv = gh * ((dh - mean) * inv) + bh;
      const float hz = fz * hf[t];
      const float hn = zreg * hz + (1.f - zreg) * tanhf(s1h_c + hhv);
      const float hc = (xm > 0) ? hn : hz;
      hf[t] = hc;
      const float ho = __shfl_xor(hc, 1);
      if (!(t & 1)) {
        h2 p2; p2[0] = (_Float16)hc; p2[1] = (_Float16)ho;
        ((h2*)(sm + OFFM_H2))[t >> 1] = p2;
      }
    }
    wg_barrier();  // B4

    s1z_c = s1z_n; s1h_c = s1h_n; fz_c = fz_n; xm_c = xm_n;
  }
  if (t < 256) out[((((size_t)b << 11) | 2047)) * 256 + t] = hf[t];
}

// ---------------------------------------------------------------------------
extern "C" void kernel_launch(void* const* d_in, const int* in_sizes, int n_in,
                              void* d_out, int out_size, void* d_ws, size_t ws_size,
                              hipStream_t stream)
{
  (void)in_sizes; (void)n_in; (void)out_size;
  const float* x       = (const float*)d_in[0];
  const int*   mask    = (const int*)d_in[1];
  const float* W       = (const float*)d_in[2];
  const float* U       = (const float*)d_in[3];
  const float* bvec    = (const float*)d_in[4];
  const float* gammas  = (const float*)d_in[5];
  const float* betas   = (const float*)d_in[6];
  const float* W_EP    = (const float*)d_in[7];
  const float* U_EP    = (const float*)d_in[8];
  const float* b_EP    = (const float*)d_in[9];
  const float* gammasE = (const float*)d_in[10];
  const float* betasE  = (const float*)d_in[11];
  const float* W1_EP   = (const float*)d_in[12];
  const float* b1_EP   = (const float*)d_in[13];
  float* out = (float*)d_out;

  const size_t NR = 131072;                 // B*T
  const size_t S1_SZ    = NR * 768 * 2;     // f16
  const size_t S1E64_SZ = NR * 192 * 8;     // f64
  const size_t S1E32_SZ = NR * 192 * 4;     // f32 fallback
  const size_t WSMALL = 262144 + 131072 + 393216 + 196608 + 524288;
  const int s1e64 = (ws_size >= S1_SZ + S1E64_SZ + WSMALL) ? 1 : 0;
  const size_t S1E_SZ = s1e64 ? S1E64_SZ : S1E32_SZ;
  if (ws_size < S1_SZ + S1E32_SZ + WSMALL) return;  // cannot run

  char* ws = (char*)d_ws;
  size_t off = 0;
  void* s1e      = (void*)(ws + off);      off += S1E_SZ;
  _Float16* s1   = (_Float16*)(ws + off);  off += S1_SZ;
  _Float16* uzr  = (_Float16*)(ws + off);  off += 262144;
  _Float16* uh   = (_Float16*)(ws + off);  off += 131072;
  _Float16* wt   = (_Float16*)(ws + off);  off += 393216;
  float* wept    = (float*)(ws + off);     off += 196608;
  float* fzw     = (float*)(ws + off);     off += 524288;

  prep_kernel<<<dim3(1728), dim3(256), 0, stream>>>(
      W, U, W_EP, wt, uzr, uh, wept);
  ph1_ep_kernel<<<dim3(8192), dim3(192), 0, stream>>>(
      x, wept, b_EP, gammasE, betasE, s1e, s1e64);
  ep_scan_kernel<<<dim3(64), dim3(64), 0, stream>>>(
      U_EP, (const void*)s1e, s1e64, mask,
      gammasE + 192, betasE + 192, W1_EP, b1_EP, out, fzw);
  ph1_main_kernel<<<dim3(8192), dim3(256), 0, stream>>>(
      x, wt, bvec, gammas, betas, s1);

  hipFuncSetAttribute(reinterpret_cast<const void*>(main_scan_kernel),
                      hipFuncAttributeMaxDynamicSharedMemorySize, SCANM_LDS_BYTES);
  main_scan_kernel<<<dim3(64), dim3(512), SCANM_LDS_BYTES, stream>>>(
      uzr, uh, s1, mask, fzw, gammas + 768, betas + 768, out);
}